// Round 10
// baseline (187.434 us; speedup 1.0000x reference)
//
#include <hip/hip_runtime.h>
#include <hip/hip_bf16.h>
#include <math.h>

#define B_ 2
#define N_ 2048
#define C_ 1024
#define H_ 16
#define G_ 4
#define D_ 64
#define QKV_N 1152   // 1024 q + 64 ksum + 64 vsum

using short8  = __attribute__((ext_vector_type(8))) short;
using short4v = __attribute__((ext_vector_type(4))) short;
using float4v = __attribute__((ext_vector_type(4))) float;

#if __has_builtin(__builtin_amdgcn_mfma_f32_16x16x16_bf16)
#define MFMA16K16(A, B, C) __builtin_amdgcn_mfma_f32_16x16x16_bf16(A, B, C, 0, 0, 0)
#else
#define MFMA16K16(A, B, C) __builtin_amdgcn_mfma_f32_16x16x16bf16_1k(A, B, C, 0, 0, 0)
#endif

__device__ __forceinline__ ushort f2bf(float f) {
    union { float f; unsigned u; } v; v.f = f;
    unsigned r = (v.u + 0x7FFF + ((v.u >> 16) & 1)) >> 16;  // RNE
    return (ushort)r;
}
__device__ __forceinline__ float bf2f(ushort u) {
    union { unsigned u; float f; } t; t.u = ((unsigned)u) << 16; return t.f;
}
__device__ __forceinline__ unsigned pack_bf16(float a, float b) {
#if __has_builtin(__builtin_amdgcn_cvt_pk_bf16_f32)
    auto t = __builtin_amdgcn_cvt_pk_bf16_f32(a, b);
    unsigned r; __builtin_memcpy(&r, &t, 4); return r;
#else
    return (unsigned)f2bf(a) | ((unsigned)f2bf(b) << 16);
#endif
}
__device__ __forceinline__ float fexp2(float x) {
#if __has_builtin(__builtin_amdgcn_exp2f)
    return __builtin_amdgcn_exp2f(x);
#else
    return exp2f(x);
#endif
}

// ---------------------------------------------------------------------------
// Fused prep (one launch):
//   blocks [0,4096)     : x fp32 -> bf16
//   [4096,4352)         : w_q^T   -> wqkvT rows 0..1023
//   [4352,4608)         : w_out^T -> woutT
//   [4608,4624)         : kv weight g-sum + transpose -> wqkvT rows 1024..1151
// ---------------------------------------------------------------------------
__device__ void tconv_body(const float* __restrict__ src, ushort* __restrict__ dst,
                           int K, int N, int bx, int by, float (*T)[65]) {
    const int n0 = bx * 64, k0 = by * 64;
    const int tid = threadIdx.x;
    #pragma unroll
    for (int s = 0; s < 16; ++s) {
        int idx = tid + s * 256; int r = idx >> 6, cc = idx & 63;
        T[r][cc] = src[(size_t)(k0 + r) * N + n0 + cc];
    }
    __syncthreads();
    #pragma unroll
    for (int s = 0; s < 16; ++s) {
        int idx = tid + s * 256; int r = idx >> 6, cc = idx & 63;
        dst[(size_t)(n0 + r) * K + k0 + cc] = f2bf(T[cc][r]);
    }
}

__global__ void prep(const float* __restrict__ x, const float* __restrict__ w_q,
                     const float* __restrict__ w_kv, const float* __restrict__ w_out,
                     ushort* __restrict__ xb, ushort* __restrict__ wqkvT,
                     ushort* __restrict__ woutT) {
    __shared__ float T[64][65];
    const int blk = blockIdx.x, tid = threadIdx.x;
    if (blk < 4096) {
        int i = blk * 1024 + tid * 4;
        float4 v = *(const float4*)(x + i);
        ushort4 o;
        o.x = f2bf(v.x); o.y = f2bf(v.y); o.z = f2bf(v.z); o.w = f2bf(v.w);
        *(ushort4*)(xb + i) = o;
    } else if (blk < 4352) {
        int idx = blk - 4096;
        tconv_body(w_q, wqkvT, C_, C_, idx & 15, idx >> 4, T);
    } else if (blk < 4608) {
        int idx = blk - 4352;
        tconv_body(w_out, woutT, C_, C_, idx & 15, idx >> 4, T);
    } else {
        // kv g-sum + transpose: wqkvT[1024+d][k] = sum_g w_kv[k][g*64+d],
        //                       wqkvT[1088+d][k] = sum_g w_kv[k][256+g*64+d]
        const int k0 = (blk - 4608) * 64;
        #pragma unroll
        for (int it = 0; it < 4; ++it) {
            int p = tid + it * 256;              // 1024 (kk, d-quad) pairs
            int kk = p >> 4, d4 = (p & 15) * 4;
            float ks[4] = {0, 0, 0, 0}, vs[4] = {0, 0, 0, 0};
            #pragma unroll
            for (int g = 0; g < G_; ++g) {
                float4 a = *(const float4*)(w_kv + (size_t)(k0 + kk) * 512 + g * 64 + d4);
                float4 b = *(const float4*)(w_kv + (size_t)(k0 + kk) * 512 + 256 + g * 64 + d4);
                ks[0] += a.x; ks[1] += a.y; ks[2] += a.z; ks[3] += a.w;
                vs[0] += b.x; vs[1] += b.y; vs[2] += b.z; vs[3] += b.w;
            }
            #pragma unroll
            for (int e = 0; e < 4; ++e) {
                wqkvT[(size_t)(1024 + d4 + e) * C_ + k0 + kk] = f2bf(ks[e]);
                wqkvT[(size_t)(1088 + d4 + e) * C_ + k0 + kk] = f2bf(vs[e]);
            }
        }
    }
}

// ---------------------------------------------------------------------------
// bf16 MFMA GEMM, 64x64 tile, BK=64, global_load_lds(16) staging with
// global-side XOR chunk swizzle (conflict-free, loop-invariant read offsets).
// C[M][N] = A[M][K] @ Bt[N][K]^T.
// ---------------------------------------------------------------------------
template <bool F32OUT>
__global__ __launch_bounds__(256) void gemm64(const ushort* __restrict__ A,
                                              const ushort* __restrict__ Bt,
                                              void* __restrict__ Cv,
                                              int M, int N, int K) {
    __shared__ __align__(16) ushort As[64 * 64];
    __shared__ __align__(16) ushort Bs[64 * 64];

    const int tid = threadIdx.x, wave = tid >> 6, lane = tid & 63;
    const int g = lane >> 4, c = lane & 15;
    const int wr = wave >> 1, wc = wave & 1;
    const int m0 = blockIdx.y * 64, n0 = blockIdx.x * 64;

    const int lr8 = lane >> 3, lq8 = lane & 7;
    const int gchunk = (lq8 ^ lr8) * 8;
    const ushort* pa = A  + (size_t)(m0 + wave * 16 + lr8) * K + gchunk;
    const ushort* pb = Bt + (size_t)(n0 + wave * 16 + lr8) * K + gchunk;

    float4v acc[2][2] = {{{0,0,0,0},{0,0,0,0}},{{0,0,0,0},{0,0,0,0}}};

    for (int k0 = 0; k0 < K; k0 += 64) {
        #pragma unroll
        for (int t = 0; t < 2; ++t) {
            __builtin_amdgcn_global_load_lds(
                (const __attribute__((address_space(1))) void*)(pa + (size_t)t * 8 * K + k0),
                (__attribute__((address_space(3))) void*)&As[(wave * 16 + t * 8) * 64], 16, 0, 0);
            __builtin_amdgcn_global_load_lds(
                (const __attribute__((address_space(1))) void*)(pb + (size_t)t * 8 * K + k0),
                (__attribute__((address_space(3))) void*)&Bs[(wave * 16 + t * 8) * 64], 16, 0, 0);
        }
        __syncthreads();

        #pragma unroll
        for (int kk = 0; kk < 2; ++kk) {
            const int c7 = c & 7;
            short8 af0 = *(const short8*)&As[(wr * 32 + c) * 64 + ((kk * 4 + g) ^ c7) * 8];
            short8 af1 = *(const short8*)&As[(wr * 32 + 16 + c) * 64 + ((kk * 4 + g) ^ c7) * 8];
            short8 bf0 = *(const short8*)&Bs[(wc * 32 + c) * 64 + ((kk * 4 + g) ^ c7) * 8];
            short8 bf1 = *(const short8*)&Bs[(wc * 32 + 16 + c) * 64 + ((kk * 4 + g) ^ c7) * 8];
            acc[0][0] = __builtin_amdgcn_mfma_f32_16x16x32_bf16(af0, bf0, acc[0][0], 0, 0, 0);
            acc[0][1] = __builtin_amdgcn_mfma_f32_16x16x32_bf16(af0, bf1, acc[0][1], 0, 0, 0);
            acc[1][0] = __builtin_amdgcn_mfma_f32_16x16x32_bf16(af1, bf0, acc[1][0], 0, 0, 0);
            acc[1][1] = __builtin_amdgcn_mfma_f32_16x16x32_bf16(af1, bf1, acc[1][1], 0, 0, 0);
        }
        __syncthreads();
    }

    #pragma unroll
    for (int a = 0; a < 2; ++a)
        #pragma unroll
        for (int bb = 0; bb < 2; ++bb)
            #pragma unroll
            for (int r = 0; r < 4; ++r) {
                int rowi = m0 + wr * 32 + a * 16 + 4 * g + r;
                int coli = n0 + wc * 32 + bb * 16 + c;
                if (F32OUT) ((float*)Cv)[(size_t)rowi * N + coli] = acc[a][bb][r];
                else ((ushort*)Cv)[(size_t)rowi * N + coli] = f2bf(acc[a][bb][r]);
            }
}

// ---------------------------------------------------------------------------
// rope_kv: qkvb cols 1024..1087 = Khat, 1088..1151 = Vhat (already g-summed).
// Kt[b][j][d] = rope(Khat); VtT[b][d][j] = Vhat (bf16 pass-through).
// ---------------------------------------------------------------------------
__global__ void rope_kv(const ushort* __restrict__ qkvb,
                        ushort* __restrict__ Kt, ushort* __restrict__ VtT) {
    const int wid = threadIdx.x >> 6, d = threadIdx.x & 63;
    const int rowg = blockIdx.x * 4 + wid;          // b*N + n
    const int n = rowg & (N_ - 1), b = rowg >> 11;

    const ushort* base = qkvb + (size_t)rowg * QKV_N + 1024;
    float ks = bf2f(base[d]);
    float partner = __shfl_xor(ks, 32, 64);
    float rh = (d < 32) ? -partner : partner;
    float ang = (float)n * __powf(10000.0f, -(float)(d & 31) * (1.0f / 32.0f));
    float sn, cs; __sincosf(ang, &sn, &cs);

    Kt[(size_t)rowg * 64 + d] = f2bf(ks * cs + rh * sn);
    VtT[((size_t)b * 64 + d) * N_ + n] = base[64 + d];
}

// ---------------------------------------------------------------------------
// Flash attention v10: attn9's S^T scheme, but 32 Q-rows/wave (qt 0..15) ->
// grid 1024 blocks = 4 blocks/CU = 4 waves/SIMD (was 2). Everything else
// (XOR-swizzled K/V LDS, register staging, PV via 16x16x16, K-split x2)
// byte-identical.
// ---------------------------------------------------------------------------
#define QSCALE 0.18033688011112042f   // 0.125 * log2(e)

__global__ __launch_bounds__(256) void attn10(
        const ushort* __restrict__ qkvb, const ushort* __restrict__ Kt,
        const ushort* __restrict__ VtT,
        ushort* __restrict__ oP0, ushort* __restrict__ oP1,
        float* __restrict__ lP0, float* __restrict__ lP1) {
    const int s  = blockIdx.x & 1;
    const int qt = (blockIdx.x >> 1) & 15;
    const int h  = (blockIdx.x >> 5) & 15;
    const int b  = blockIdx.x >> 9;
    const int tid = threadIdx.x, wave = tid >> 6, lane = tid & 63;
    const int g = lane >> 4, c = lane & 15;

    __shared__ __align__(16) ushort Ksh[64 * 64];   // [j-local][d], XOR-swizzled
    __shared__ __align__(16) ushort Vsh[64 * 64];   // [d][j-local], XOR-swizzled

    ushort* oPs = s ? oP1 : oP0;
    float*  lPs = s ? lP1 : lP0;

    const int i0 = qt * 128 + wave * 32;
    float invf[8];
    #pragma unroll
    for (int i = 0; i < 8; ++i)
        invf[i] = __powf(10000.0f, -(float)(8 * g + i) * (1.0f / 32.0f));

    short8 qf[2][2];
    #pragma unroll
    for (int a = 0; a < 2; ++a) {
        const int row = i0 + a * 16 + c;
        const ushort* qrow = qkvb + (size_t)(b * N_ + row) * QKV_N + h * 64;
        short8 raw0 = *(const short8*)(qrow + 8 * g);
        short8 raw1 = *(const short8*)(qrow + 32 + 8 * g);
        #pragma unroll
        for (int i = 0; i < 8; ++i) {
            float f0 = bf2f((ushort)raw0[i]), f1 = bf2f((ushort)raw1[i]);
            float sn, cs; __sincosf((float)row * invf[i], &sn, &cs);
            qf[a][0][i] = (short)f2bf((f0 * cs - f1 * sn) * QSCALE);
            qf[a][1][i] = (short)f2bf((f1 * cs + f0 * sn) * QSCALE);
        }
    }

    float4v o[2][4];
    #pragma unroll
    for (int a = 0; a < 2; ++a)
        #pragma unroll
        for (int f = 0; f < 4; ++f) o[a][f] = {0, 0, 0, 0};
    float ll[2] = {0.f, 0.f};

    const ushort* Kb = Kt  + (size_t)b * N_ * 64;
    const ushort* Vb = VtT + (size_t)b * 64 * N_;
    const int lr8 = lane >> 3, lq8 = lane & 7;
    const int wpos = (lq8 ^ lr8) * 8;
    const int j0 = s * (N_ / 2);
    const int NT = (N_ / 2) / 64;

    short8 kr0 = *(const short8*)(Kb + (size_t)(j0 + wave * 16 + lr8) * 64 + lq8 * 8);
    short8 kr1 = *(const short8*)(Kb + (size_t)(j0 + wave * 16 + 8 + lr8) * 64 + lq8 * 8);
    short8 vr0 = *(const short8*)(Vb + (size_t)(wave * 16 + lr8) * N_ + j0 + lq8 * 8);
    short8 vr1 = *(const short8*)(Vb + (size_t)(wave * 16 + 8 + lr8) * N_ + j0 + lq8 * 8);

    for (int t = 0; t < NT; ++t) {
        __syncthreads();
        *(short8*)&Ksh[(wave * 16 + lr8) * 64 + wpos]     = kr0;
        *(short8*)&Ksh[(wave * 16 + 8 + lr8) * 64 + wpos] = kr1;
        *(short8*)&Vsh[(wave * 16 + lr8) * 64 + wpos]     = vr0;
        *(short8*)&Vsh[(wave * 16 + 8 + lr8) * 64 + wpos] = vr1;
        __syncthreads();
        if (t + 1 < NT) {
            const int jn = j0 + (t + 1) * 64;
            kr0 = *(const short8*)(Kb + (size_t)(jn + wave * 16 + lr8) * 64 + lq8 * 8);
            kr1 = *(const short8*)(Kb + (size_t)(jn + wave * 16 + 8 + lr8) * 64 + lq8 * 8);
            vr0 = *(const short8*)(Vb + (size_t)(wave * 16 + lr8) * N_ + jn + lq8 * 8);
            vr1 = *(const short8*)(Vb + (size_t)(wave * 16 + 8 + lr8) * N_ + jn + lq8 * 8);
        }

        #pragma unroll
        for (int jt4 = 0; jt4 < 4; ++jt4) {
            const int R = jt4 * 16 + c;
            short8 kf0 = *(const short8*)&Ksh[R * 64 + ((g ^ (c & 7)) * 8)];
            short8 kf1 = *(const short8*)&Ksh[R * 64 + (((g ^ 4) ^ (c & 7)) * 8)];
            short4v vf[4];
            #pragma unroll
            for (int f = 0; f < 4; ++f)
                vf[f] = *(const short4v*)&Vsh[(16 * f + c) * 64 +
                          (((jt4 * 2 + (g >> 1)) ^ (c & 7)) * 8) + (g & 1) * 4];

            #pragma unroll
            for (int a = 0; a < 2; ++a) {
                float4v st = {0, 0, 0, 0};
                st = __builtin_amdgcn_mfma_f32_16x16x32_bf16(kf0, qf[a][0], st, 0, 0, 0);
                st = __builtin_amdgcn_mfma_f32_16x16x32_bf16(kf1, qf[a][1], st, 0, 0, 0);
                float p0 = fexp2(st[0]), p1 = fexp2(st[1]);
                float p2 = fexp2(st[2]), p3 = fexp2(st[3]);
                ll[a] += (p0 + p1) + (p2 + p3);
                union { unsigned u[2]; short4v v; } pk;
                pk.u[0] = pack_bf16(p0, p1);
                pk.u[1] = pack_bf16(p2, p3);
                #pragma unroll
                for (int f = 0; f < 4; ++f)
                    o[a][f] = MFMA16K16(vf[f], pk.v, o[a][f]);
            }
        }
    }

    #pragma unroll
    for (int a = 0; a < 2; ++a) {
        float lt = ll[a];
        lt += __shfl_xor(lt, 16, 64);
        lt += __shfl_xor(lt, 32, 64);
        const int row = i0 + a * 16 + c;
        if (g == 0) lPs[(size_t)(b * N_ + row) * 16 + h] = lt;
        #pragma unroll
        for (int f = 0; f < 4; ++f) {
            ushort4 w;
            w.x = f2bf(o[a][f][0]); w.y = f2bf(o[a][f][1]);
            w.z = f2bf(o[a][f][2]); w.w = f2bf(o[a][f][3]);
            *(ushort4*)(oPs + (size_t)(b * N_ + row) * 1024 + h * 64 + 16 * f + 4 * g) = w;
        }
    }
}

// ---------------------------------------------------------------------------
// Combine: ao = (oP0 + oP1) / (lP0 + lP1), bf16 out (in-place over oP0 ok)
// ---------------------------------------------------------------------------
__global__ void combine(const ushort* __restrict__ oP0, const ushort* __restrict__ oP1,
                        const float* __restrict__ lP0, const float* __restrict__ lP1,
                        ushort* __restrict__ ao) {
    const int e = (blockIdx.x * 256 + threadIdx.x) * 4;
    const int row = e >> 10, hh = (e >> 6) & 15;
    const float inv = 1.0f / (lP0[row * 16 + hh] + lP1[row * 16 + hh]);
    ushort4 a = *(const ushort4*)(oP0 + e);
    ushort4 b = *(const ushort4*)(oP1 + e);
    ushort4 r;
    r.x = f2bf((bf2f(a.x) + bf2f(b.x)) * inv);
    r.y = f2bf((bf2f(a.y) + bf2f(b.y)) * inv);
    r.z = f2bf((bf2f(a.z) + bf2f(b.z)) * inv);
    r.w = f2bf((bf2f(a.w) + bf2f(b.w)) * inv);
    *(ushort4*)(ao + e) = r;
}

// ---------------------------------------------------------------------------
extern "C" void kernel_launch(void* const* d_in, const int* in_sizes, int n_in,
                              void* d_out, int out_size, void* d_ws, size_t ws_size,
                              hipStream_t stream) {
    const float* x     = (const float*)d_in[0];
    const float* w_q   = (const float*)d_in[1];
    const float* w_kv  = (const float*)d_in[2];
    const float* w_out = (const float*)d_in[3];
    float* out = (float*)d_out;

    const int M = B_ * N_;                               // 4096
    ushort* xb    = (ushort*)d_ws;                       // 4096*1024  (-> oP0 -> ao)
    ushort* wqkvT = xb    + (size_t)M * C_;              // 1152*1024
    ushort* woutT = wqkvT + (size_t)QKV_N * C_;          // 1024*1024
    ushort* qkvb  = woutT + (size_t)C_ * C_;             // 4096*1152
    ushort* Kt    = qkvb  + (size_t)M * QKV_N;           // 2*2048*64
    ushort* VtT   = Kt    + (size_t)B_ * N_ * D_;        // 2*64*2048
    ushort* oP1   = VtT   + (size_t)B_ * D_ * N_;        // 4096*1024 bf16 partial
    float*  lP0   = (float*)(oP1 + (size_t)M * C_);      // 4096*16 fp32
    float*  lP1   = lP0 + (size_t)M * H_;
    ushort* oP0   = xb;   // xb dead after qkv GEMM
    ushort* ao    = xb;   // combine writes in-place over oP0

    prep<<<4624, 256, 0, stream>>>(x, w_q, w_kv, w_out, xb, wqkvT, woutT);
    gemm64<false><<<dim3(QKV_N / 64, M / 64), 256, 0, stream>>>(xb, wqkvT, qkvb, M, QKV_N, C_);
    rope_kv<<<M / 4, 256, 0, stream>>>(qkvb, Kt, VtT);
    attn10<<<B_ * H_ * (N_ / 128) * 2, 256, 0, stream>>>(qkvb, Kt, VtT, oP0, oP1, lP0, lP1);
    combine<<<(M * C_) / 1024, 256, 0, stream>>>(oP0, oP1, lP0, lP1, ao);
    gemm64<true><<<dim3(C_ / 64, M / 64), 256, 0, stream>>>(ao, woutT, out, M, C_, C_);
}